// Round 1
// baseline (9900.330 us; speedup 1.0000x reference)
//
#include <hip/hip_runtime.h>
#include <cmath>

// TimeLSTMCell B=64, S=512, E=256, H=512.
// Round 5: replace flag-barrier sync with TAG-EMBEDDED DATAFLOW.
//
// Cross-WG state exchange: one 64-bit atomic word per (batch, col):
//   { tag = step (hi 32) | c bf16 (bits 16..31) | h bf16 (bits 0..15) }
// written with relaxed AGENT-scope atomics into parity (even/odd) buffers.
// Readers poll each word for tag == s: the data load IS the sync. No flags,
// no 64-WG barrier, no reset pass. Safety: tag s+2 overwrites tag-s words
// only after every WG published tag s+1, which requires every WG to have
// READ all tag-s words (2-buffer parity + monotonic tags, ABA-free, S=512).
//
// Also this round: LDS bank-conflict cleanup —
//   * Cred/Dred spill swizzled  [m*16 + ((n+m)&15)]  (was 4-way conflicted)
//   * h/c/x staging writes as uint4 (ds_write_b128, was stride-8 b32 = 8-way)
//
// MFMA 16x16x32 bf16 layouts (m89/m91/m120 verified):
//   A: m=lane&15, k=(lane>>4)*8+j   B: n=lane&15, k=(lane>>4)*8+j
//   D: n=lane&15, m=(lane>>4)*4+reg
// fp32 kept for biases, c carry (c_own), pointwise math; bf16 only in GEMM
// operands and the state mirrors (same rounding path as prev round).

typedef short bf16x8 __attribute__((ext_vector_type(8)));
typedef float f32x4  __attribute__((ext_vector_type(4)));

#define Bdim 64
#define Sdim 512
#define Edim 256
#define Hdim 512
#define NWG  256
#define NT   512

// ws layout (bytes). Total 4718592 (~4.5 MB).
#define WS_MIR   0                        // mirror[2][B][H] u64 = 524288 B
#define MIRQ     (Bdim * Hdim)            // qwords per parity buffer
#define WS_WFRAG 524288                   // 64cg*2tile*24k*64lane*8 bf16 = 3 MB
#define WS_DFRAG (WS_WFRAG + 3145728)     // 64cg*16k*64lane*8 bf16 = 1 MB

__device__ __forceinline__ unsigned long long ld_dev_u64(const unsigned long long* p) {
    return __hip_atomic_load(p, __ATOMIC_RELAXED, __HIP_MEMORY_SCOPE_AGENT);
}
__device__ __forceinline__ void st_dev_u64(unsigned long long* p, unsigned long long v) {
    __hip_atomic_store(p, v, __ATOMIC_RELAXED, __HIP_MEMORY_SCOPE_AGENT);
}
__device__ __forceinline__ unsigned short f2bf(float f) {
    union { float f; unsigned u; } v; v.f = f;
    return (unsigned short)((v.u + 0x7FFFu + ((v.u >> 16) & 1u)) >> 16);  // RNE
}
__device__ __forceinline__ unsigned pack2(float lo, float hi) {
    return (unsigned)f2bf(lo) | ((unsigned)f2bf(hi) << 16);
}

// ---------------- pre-pass: pack weights, zero mirrors ----------------------
__global__ __launch_bounds__(256) void tlstm_prep(
    const float* __restrict__ Wall, const float* __restrict__ Uall,
    const float* __restrict__ Wd, unsigned char* __restrict__ ws)
{
    const int w = blockIdx.x, t = threadIdx.x;
    unsigned short* Wfrag = (unsigned short*)(ws + WS_WFRAG);
    unsigned short* Dfrag = (unsigned short*)(ws + WS_DFRAG);
    const int l = t & 63, ks = t >> 6, nn = l & 15, q = l >> 4;

    if (w < 128) {                       // gate fragments: WG = (cg, tile)
        const int cg = w >> 1, tile = w & 1;
        const int g = tile * 2 + (nn >> 3), jj = nn & 7;
        const int row = g * Hdim + cg * 8 + jj;
        for (int i = 0; i < 6; ++i) {
            const int kp = ks * 6 + i;   // 0..23
            const float* src = (kp < 16)
                ? Wall + (size_t)row * Hdim + kp * 32 + q * 8
                : Uall + (size_t)row * Edim + (kp - 16) * 32 + q * 8;
            unsigned* dst = (unsigned*)(Wfrag
                + (((size_t)(cg * 2 + tile) * 24 + kp) * 64 + l) * 8);
            #pragma unroll
            for (int p = 0; p < 4; ++p) dst[p] = pack2(src[2*p], src[2*p+1]);
        }
    } else if (w < 192) {                // d fragments: WG = cg
        const int cg = w - 128;
        int row = cg * 8 + nn; if (row > 511) row = 511;  // clamp (cols 8..15 unused)
        for (int i = 0; i < 4; ++i) {
            const int kp = ks * 4 + i;   // 0..15
            const float* src = Wd + (size_t)row * Hdim + kp * 32 + q * 8;
            unsigned* dst = (unsigned*)(Dfrag + (((size_t)cg * 16 + kp) * 64 + l) * 8);
            #pragma unroll
            for (int p = 0; p < 4; ++p) dst[p] = pack2(src[2*p], src[2*p+1]);
        }
    } else {                             // zero both mirror parities (524288 B)
        const int idx = (w - 192) * 256 + t;          // 0..16383
        uint4* z = (uint4*)(ws + WS_MIR);
        z[idx] = make_uint4(0, 0, 0, 0);              // 32768 uint4 total
        z[idx + 16384] = make_uint4(0, 0, 0, 0);
        // parity-0 zeros ARE the valid step-0 state: h=c=0 bf16, tag=0.
        // parity-1 zeros have tag 0 != 1 -> readers wait for real writes.
    }
}

// ------------------------------- main kernel --------------------------------
__global__ __launch_bounds__(NT, 2) void tlstm_mfma(
    const float* __restrict__ x,       // [B,S,E] fp32
    const float* __restrict__ ts,      // [B,S]
    const float* __restrict__ Wall_b,  // [4H]
    const float* __restrict__ Uall_b,  // [4H]
    const float* __restrict__ Wd_b,    // [H]
    float* __restrict__ out,           // [B,S,H] | h_f | c_f (write-only)
    unsigned char* __restrict__ ws)
{
    __shared__ __align__(16) unsigned short h_sb[16 * 520];   // bf16, row pad +8
    __shared__ __align__(16) unsigned short c_sb[16 * 520];
    __shared__ __align__(16) unsigned short x_sb[16 * 264];
    __shared__ float Cred[2][4][256];
    __shared__ float Dred[8][256];
    __shared__ float act[4 * 128];
    __shared__ float cs1v[128];
    __shared__ float c_own[128];                // fp32 c carry for own cols
    __shared__ float decv[16];

    const unsigned short* Wfrag = (const unsigned short*)(ws + WS_WFRAG);
    const unsigned short* Dfrag = (const unsigned short*)(ws + WS_DFRAG);
    unsigned long long* mir = (unsigned long long*)(ws + WS_MIR);

    const int t    = threadIdx.x;
    const int bg   = blockIdx.x >> 6, cg = blockIdx.x & 63;
    const int b0   = bg * 16, j0 = cg * 8;
    const int w    = t >> 6, lane = t & 63, q = lane >> 4, nn = lane & 15;
    const int tile = w >> 2, kbase = (w & 3) * 6;

    // ---- weights -> registers, once (32 VGPRs; L2-hot loads) ----
    bf16x8 bw[6];
    #pragma unroll
    for (int i = 0; i < 6; ++i)
        bw[i] = *(const bf16x8*)(Wfrag
            + (((size_t)(cg * 2 + tile) * 24 + kbase + i) * 64 + lane) * 8);
    bf16x8 bd[2];
    #pragma unroll
    for (int i = 0; i < 2; ++i)
        bd[i] = *(const bf16x8*)(Dfrag + (((size_t)cg * 16 + w * 2 + i) * 64 + lane) * 8);

    const int srow = t >> 5, sc32 = t & 31;    // staging role: row 0..15, col chunk

    // stage x[b0..b0+16, sx, :] -> x_sb (plain cached loads, fp32 -> bf16)
    auto stage_x = [&](int sx) {
        const float4* xp = (const float4*)(x + ((size_t)(b0 + srow) * Sdim + sx) * Edim + sc32 * 8);
        float4 v0 = xp[0], v1 = xp[1];
        *(uint4*)((unsigned*)x_sb + srow * 132 + sc32 * 4) =
            make_uint4(pack2(v0.x, v0.y), pack2(v0.z, v0.w),
                       pack2(v1.x, v1.y), pack2(v1.z, v1.w));
    };

    // stage h,c for step si: poll tagged mirror words, unpack into LDS
    auto stage_hc = [&](int si) {
        const unsigned tg = (unsigned)si;
        const unsigned long long* src = mir + (size_t)(si & 1) * MIRQ
            + (size_t)(b0 + srow) * Hdim + sc32 * 16;
        unsigned long long v[16];
        #pragma unroll
        for (int i = 0; i < 16; ++i) v[i] = ld_dev_u64(src + i);
        for (;;) {
            unsigned bad = 0;
            #pragma unroll
            for (int i = 0; i < 16; ++i)
                bad |= ((unsigned)(v[i] >> 32) != tg) ? (1u << i) : 0u;
            if (!bad) break;
            __builtin_amdgcn_s_sleep(1);
            #pragma unroll
            for (int i = 0; i < 16; ++i)
                if (bad & (1u << i)) v[i] = ld_dev_u64(src + i);
        }
        unsigned hw[8], cw[8];
        #pragma unroll
        for (int i = 0; i < 8; ++i) {
            const unsigned lo0 = (unsigned)v[2 * i], lo1 = (unsigned)v[2 * i + 1];
            hw[i] = (lo0 & 0xFFFFu) | (lo1 << 16);
            cw[i] = (lo0 >> 16) | (lo1 & 0xFFFF0000u);
        }
        uint4* hq = (uint4*)((unsigned*)h_sb + srow * 260 + sc32 * 8);
        uint4* cq = (uint4*)((unsigned*)c_sb + srow * 260 + sc32 * 8);
        hq[0] = make_uint4(hw[0], hw[1], hw[2], hw[3]);
        hq[1] = make_uint4(hw[4], hw[5], hw[6], hw[7]);
        cq[0] = make_uint4(cw[0], cw[1], cw[2], cw[3]);
        cq[1] = make_uint4(cw[4], cw[5], cw[6], cw[7]);
    };

    if (t < 128) c_own[t] = 0.0f;
    stage_x(0);
    stage_hc(0);           // prep's zeros are tag-0-valid -> no wait
    __syncthreads();

    for (int s = 0;; ++s) {
        // ---- MFMA: 6 gate k-steps + 2 d k-steps, B in registers ----
        f32x4 accg = {0.f, 0.f, 0.f, 0.f}, accd = {0.f, 0.f, 0.f, 0.f};
        #pragma unroll
        for (int i = 0; i < 6; ++i) {
            const int kk = kbase + i;
            const unsigned short* asrc = (kk < 16)
                ? (h_sb + nn * 520 + kk * 32 + q * 8)
                : (x_sb + nn * 264 + (kk - 16) * 32 + q * 8);
            bf16x8 av = *(const bf16x8*)asrc;
            accg = __builtin_amdgcn_mfma_f32_16x16x32_bf16(av, bw[i], accg, 0, 0, 0);
        }
        #pragma unroll
        for (int i = 0; i < 2; ++i) {
            const int kd = w * 2 + i;
            bf16x8 av = *(const bf16x8*)(c_sb + nn * 520 + kd * 32 + q * 8);
            accd = __builtin_amdgcn_mfma_f32_16x16x32_bf16(av, bd[i], accd, 0, 0, 0);
        }

        // ---- spill partials to LDS, bank-swizzled (D: m = q*4+r, n = nn) ----
        #pragma unroll
        for (int r = 0; r < 4; ++r) {
            const int m = q * 4 + r;
            const int sl = m * 16 + ((nn + m) & 15);
            Cred[tile][w & 3][sl] = accg[r];
            Dred[w][sl] = accd[r];
        }
        __syncthreads();

        // ---- reduce + biases + activations ----
        {
            const int tl = t >> 8, pos = t & 255;
            const int m = pos >> 4, n = pos & 15;
            const int sl = m * 16 + ((n + m) & 15);
            float sv = Cred[tl][0][sl] + Cred[tl][1][sl]
                     + Cred[tl][2][sl] + Cred[tl][3][sl];
            const int g = tl * 2 + (n >> 3), jj = n & 7, jc = j0 + jj;
            sv += Wall_b[g * Hdim + jc] + Uall_b[g * Hdim + jc];
            act[g * 128 + m * 8 + jj] =
                (g == 3) ? tanhf(sv) : 1.0f / (1.0f + __expf(-sv));
        }
        if (t < 256) {
            const int m = t >> 4, n = t & 15;
            if (n < 8) {
                const int sl = m * 16 + ((n + m) & 15);
                float sv = 0.0f;
                #pragma unroll
                for (int ww = 0; ww < 8; ++ww) sv += Dred[ww][sl];
                cs1v[m * 8 + n] = tanhf(sv + Wd_b[j0 + n]);
            }
        }
        if (t < 16)
            decv[t] = 1.0f / __logf(2.7182818284590452f + ts[(b0 + t) * Sdim + s]);
        __syncthreads();

        // ---- finale: 64 threads, 2 cols each; tagged mirror stores ----
        if (t < 64) {
            const int bl = t >> 2, jl2 = (t & 3) * 2;
            const float dec = decv[bl];
            float hnv[2], cnv[2];
            #pragma unroll
            for (int e = 0; e < 2; ++e) {
                const int u = bl * 8 + jl2 + e;
                const float cs1  = cs1v[u];
                const float cp   = c_own[u];
                const float cadj = (cp - cs1) + cs1 * dec;
                const float f  = act[0 * 128 + u];
                const float ii = act[1 * 128 + u];
                const float oo = act[2 * 128 + u];
                const float gg = act[3 * 128 + u];
                const float cn = f * cadj + ii * gg;
                const float hn = oo * tanhf(cn);
                c_own[u] = cn; hnv[e] = hn; cnv[e] = cn;
                out[((size_t)(b0 + bl) * Sdim + s) * Hdim + j0 + jl2 + e] = hn;
            }
            if (s < Sdim - 1) {
                unsigned long long* mw = mir + (size_t)((s + 1) & 1) * MIRQ
                    + (size_t)(b0 + bl) * Hdim + (j0 + jl2);
                const unsigned long long tg = ((unsigned long long)(unsigned)(s + 1)) << 32;
                st_dev_u64(mw,     tg | (unsigned)f2bf(hnv[0]) | ((unsigned)f2bf(cnv[0]) << 16));
                st_dev_u64(mw + 1, tg | (unsigned)f2bf(hnv[1]) | ((unsigned)f2bf(cnv[1]) << 16));
            } else {
                float* hf = out + (size_t)Bdim * Sdim * Hdim;
                float* cf = hf + (size_t)Bdim * Hdim;
                #pragma unroll
                for (int e = 0; e < 2; ++e) {
                    hf[(b0 + bl) * Hdim + j0 + jl2 + e] = hnv[e];
                    cf[(b0 + bl) * Hdim + j0 + jl2 + e] = cnv[e];
                }
            }
        }

        if (s == Sdim - 1) break;

        // next-step staging: x (cached) overlaps the mirror tag-polling
        stage_x(s + 1);
        stage_hc(s + 1);
        __syncthreads();
    }
}

extern "C" void kernel_launch(void* const* d_in, const int* in_sizes, int n_in,
                              void* d_out, int out_size, void* d_ws, size_t ws_size,
                              hipStream_t stream) {
    const float* x      = (const float*)d_in[0];
    const float* ts     = (const float*)d_in[1];
    const float* Wall   = (const float*)d_in[2];
    const float* Wall_b = (const float*)d_in[3];
    const float* Uall   = (const float*)d_in[4];
    const float* Uall_b = (const float*)d_in[5];
    const float* Wd     = (const float*)d_in[6];
    const float* Wd_b   = (const float*)d_in[7];

    tlstm_prep<<<256, 256, 0, stream>>>(Wall, Uall, Wd, (unsigned char*)d_ws);
    tlstm_mfma<<<NWG, NT, 0, stream>>>(x, ts, Wall_b, Uall_b, Wd_b,
                                       (float*)d_out, (unsigned char*)d_ws);
}

// Round 2
// 2008.143 us; speedup vs baseline: 4.9301x; 4.9301x over previous
//
#include <hip/hip_runtime.h>
#include <cmath>

// TimeLSTMCell B=64, S=512, E=256, H=512.
// Round 6: revert to round-4 flag+mirror sync (tag-dataflow regressed 3.2x),
// and SHRINK THE SYNC DOMAIN: 4 groups x 16 WGs (was 4 x 64). Each WG owns
// 16 batches x 32 h-cols; each wave owns a full-K gate column tile ->
//   * gate GEMM needs NO cross-wave reduction (Cred phase deleted)
//   * LIC mirror traffic per step: 8 MB -> 2 MB (64 WGs instead of 256)
//   * convoy/poll over 16 producers instead of 64
// Weights live in VGPRs: 24 gate B-frags (96 VGPR) + 4 d B-frags (16 VGPR)
// per lane. c carry for own cols is a per-thread register (finale = 512 units
// = 512 threads). Sync mechanics identical to round 4: relaxed AGENT-scope
// atomics on bf16 mirrors (double-buffered) + per-WG padded flags.
//
// MFMA 16x16x32 bf16 layouts (m89/m91/m120 verified):
//   A: m=lane&15, k=(lane>>4)*8+j   B: n=lane&15, k=(lane>>4)*8+j
//   D: n=lane&15, m=(lane>>4)*4+reg
// fp32 kept for biases, c carry, pointwise math; bf16 only in GEMM operands
// and the state mirrors (same rounding path as round 4, absmax ~5e-3).

typedef short bf16x8 __attribute__((ext_vector_type(8)));
typedef float f32x4  __attribute__((ext_vector_type(4)));

#define Bdim 64
#define Sdim 512
#define Edim 256
#define Hdim 512
#define NWG  64
#define NT   512
#define FSTR 16

// ws layout (bytes), identical to round 4. Total ~3.95 MB.
#define WS_FLAGS 0
#define WS_HMIR0 16384
#define WS_HMIR1 (WS_HMIR0 + 65536)
#define WS_CMIR0 (WS_HMIR1 + 65536)
#define WS_CMIR1 (WS_CMIR0 + 65536)
#define WS_WFRAG (WS_CMIR1 + 65536)       // 16cg*8wv*24k*64lane*8 bf16 = 3 MB
#define WS_DFRAG (WS_WFRAG + 3145728)     // 16cg*8wv*4k*64lane*8 bf16 = 512 KB

__device__ __forceinline__ unsigned ld_dev_u32(const unsigned* p) {
    return __hip_atomic_load(p, __ATOMIC_RELAXED, __HIP_MEMORY_SCOPE_AGENT);
}
__device__ __forceinline__ void st_dev_u32(unsigned* p, unsigned v) {
    __hip_atomic_store(p, v, __ATOMIC_RELAXED, __HIP_MEMORY_SCOPE_AGENT);
}
__device__ __forceinline__ unsigned long long ld_dev_u64(const unsigned long long* p) {
    return __hip_atomic_load(p, __ATOMIC_RELAXED, __HIP_MEMORY_SCOPE_AGENT);
}
__device__ __forceinline__ unsigned short f2bf(float f) {
    union { float f; unsigned u; } v; v.f = f;
    return (unsigned short)((v.u + 0x7FFFu + ((v.u >> 16) & 1u)) >> 16);  // RNE
}
__device__ __forceinline__ unsigned pack2(float lo, float hi) {
    return (unsigned)f2bf(lo) | ((unsigned)f2bf(hi) << 16);
}
__device__ __forceinline__ float fast_tanh(float x) {
    const float ax = __builtin_fabsf(x);
    const float e  = __expf(-2.0f * ax);
    const float t  = (1.0f - e) / (1.0f + e);
    return __builtin_copysignf(t, x);
}
__device__ __forceinline__ float fast_sigmoid(float x) {
    return 1.0f / (1.0f + __expf(-x));
}

// ---------------- pre-pass: pack weights, zero mirrors/flags ----------------
__global__ __launch_bounds__(256) void tlstm_prep(
    const float* __restrict__ Wall, const float* __restrict__ Uall,
    const float* __restrict__ Wd, unsigned char* __restrict__ ws)
{
    const int w = blockIdx.x, t = threadIdx.x;
    unsigned short* Wfrag = (unsigned short*)(ws + WS_WFRAG);
    unsigned short* Dfrag = (unsigned short*)(ws + WS_DFRAG);
    const int l = t & 63, ks = t >> 6, nn = l & 15, q = l >> 4;

    if (w < 128) {                       // gate fragments: WG = (cg, wv)
        const int cg = w >> 3, wv = w & 7;
        const int G = wv * 16 + nn, g = G >> 5, jj = G & 31;
        const int row = g * Hdim + cg * 32 + jj;
        for (int i = 0; i < 6; ++i) {
            const int kp = ks * 6 + i;   // 0..23
            const float* src = (kp < 16)
                ? Wall + (size_t)row * Hdim + kp * 32 + q * 8
                : Uall + (size_t)row * Edim + (kp - 16) * 32 + q * 8;
            unsigned* dst = (unsigned*)(Wfrag
                + (((size_t)(cg * 8 + wv) * 24 + kp) * 64 + l) * 8);
            #pragma unroll
            for (int p = 0; p < 4; ++p) dst[p] = pack2(src[2*p], src[2*p+1]);
        }
    } else if (w < 192) {                // d fragments: 64 WGs, 8 frags each
        const int u = w - 128, cg = u >> 2, q4 = u & 3;
        for (int half = 0; half < 2; ++half) {
            const int wv = q4 * 2 + half;        // 0..7
            const int i  = ks;                   // 0..3
            const int dt = wv >> 2, kd = (wv & 3) * 4 + i;
            const int row = cg * 32 + dt * 16 + nn;     // Wd output col
            const float* src = Wd + (size_t)row * Hdim + kd * 32 + q * 8;
            unsigned* dst = (unsigned*)(Dfrag
                + (((size_t)(cg * 8 + wv) * 4 + i) * 64 + l) * 8);
            #pragma unroll
            for (int p = 0; p < 4; ++p) dst[p] = pack2(src[2*p], src[2*p+1]);
        }
    } else {                             // zero flags + all 4 mirrors (278528 B)
        const int idx = (w - 192) * 256 + t;          // 0..16383
        uint4* z = (uint4*)ws;
        for (int i = idx; i < 17408; i += 16384) z[i] = make_uint4(0, 0, 0, 0);
        // mirror parity-0 zeros ARE the valid step-0 state (h=c=0).
    }
}

// ------------------------------- main kernel --------------------------------
__global__ __launch_bounds__(NT, 2) void tlstm_mfma(
    const float* __restrict__ x,       // [B,S,E] fp32
    const float* __restrict__ ts,      // [B,S]
    const float* __restrict__ Wall_b,  // [4H]
    const float* __restrict__ Uall_b,  // [4H]
    const float* __restrict__ Wd_b,    // [H]
    float* __restrict__ out,           // [B,S,H] | h_f | c_f (write-only)
    unsigned char* __restrict__ ws)
{
    __shared__ __align__(16) unsigned short h_sb[16 * 520];   // bf16, row pad +8
    __shared__ __align__(16) unsigned short c_sb[16 * 520];
    __shared__ __align__(16) unsigned short x_sb[16 * 264];
    __shared__ float Dred[2][4][256];
    __shared__ float act[4 * 512];              // [gate][m*32+jj]
    __shared__ float cs1v[512];
    __shared__ float decv[16];

    int* flags = (int*)(ws + WS_FLAGS);
    const unsigned short* Wfrag = (const unsigned short*)(ws + WS_WFRAG);
    const unsigned short* Dfrag = (const unsigned short*)(ws + WS_DFRAG);

    const int t    = threadIdx.x;
    const int bg   = blockIdx.x >> 4, cg = blockIdx.x & 15;
    const int b0   = bg * 16, j0 = cg * 32;
    const int w    = t >> 6, lane = t & 63, q = lane >> 4, nn = lane & 15;

    // gate-col identity of this lane (wave w owns gate-col tile w: 16 cols)
    const int G = w * 16 + nn, g = G >> 5, jj = G & 31;
    const float bias_g = Wall_b[g * Hdim + j0 + jj] + Uall_b[g * Hdim + j0 + jj];
    // d-reduce identity (thread-indexed)
    const int rtl = t >> 8, rpos = t & 255, rm = rpos >> 4, rn = rpos & 15;
    const float bias_d = Wd_b[j0 + rtl * 16 + rn];
    // finale identity: unit t -> (batch fm, col fj)
    const int fm = t >> 5, fj = t & 31;

    // ---- weights -> registers, once (112 VGPRs; L2-hot loads) ----
    bf16x8 bw[24];
    #pragma unroll
    for (int i = 0; i < 24; ++i)
        bw[i] = *(const bf16x8*)(Wfrag
            + (((size_t)(cg * 8 + w) * 24 + i) * 64 + lane) * 8);
    bf16x8 bd[4];
    #pragma unroll
    for (int i = 0; i < 4; ++i)
        bd[i] = *(const bf16x8*)(Dfrag
            + (((size_t)(cg * 8 + w) * 4 + i) * 64 + lane) * 8);

    const int srow = t >> 5, sc32 = t & 31;    // staging role: row, chunk

    // stage x[b0..b0+16, sx, :] -> x_sb (plain cached loads, fp32 -> bf16)
    auto stage_x = [&](int sx) {
        const float4* xp = (const float4*)(x + ((size_t)(b0 + srow) * Sdim + sx) * Edim + sc32 * 8);
        float4 v0 = xp[0], v1 = xp[1];
        *(uint4*)((unsigned*)x_sb + srow * 132 + sc32 * 4) =
            make_uint4(pack2(v0.x, v0.y), pack2(v0.z, v0.w),
                       pack2(v1.x, v1.y), pack2(v1.z, v1.w));
    };

    float c_reg = 0.0f;                        // fp32 c carry for own unit
    stage_x(0);

    for (int s = 0;; ++s) {
        // ---- stage h, c (bf16 mirrors, LIC-coherent u64 loads) ----
        {
            const unsigned long long* hsrc =
                (const unsigned long long*)(ws + WS_HMIR0 + (s & 1) * 65536);
            const unsigned long long* csrc =
                (const unsigned long long*)(ws + WS_CMIR0 + (s & 1) * 65536);
            const int goff = ((b0 + srow) * 256 + sc32 * 8) >> 1;  // u64 index
            unsigned long long hv[4], cv[4];
            #pragma unroll
            for (int i = 0; i < 4; ++i) hv[i] = ld_dev_u64(hsrc + goff + i);
            #pragma unroll
            for (int i = 0; i < 4; ++i) cv[i] = ld_dev_u64(csrc + goff + i);
            unsigned* hls = (unsigned*)h_sb + srow * 260 + sc32 * 8;
            unsigned* cls = (unsigned*)c_sb + srow * 260 + sc32 * 8;
            ((ulonglong2*)hls)[0] = make_ulonglong2(hv[0], hv[1]);
            ((ulonglong2*)hls)[1] = make_ulonglong2(hv[2], hv[3]);
            ((ulonglong2*)cls)[0] = make_ulonglong2(cv[0], cv[1]);
            ((ulonglong2*)cls)[1] = make_ulonglong2(cv[2], cv[3]);
        }
        __syncthreads();

        // ---- MFMA: 24 gate k-steps (2 indep chains) + 4 d k-steps ----
        f32x4 acc0 = {0.f, 0.f, 0.f, 0.f}, acc1 = {0.f, 0.f, 0.f, 0.f};
        f32x4 accd = {0.f, 0.f, 0.f, 0.f};
        #pragma unroll
        for (int i = 0; i < 12; ++i) {
            bf16x8 av = *(const bf16x8*)(h_sb + nn * 520 + i * 32 + q * 8);
            acc0 = __builtin_amdgcn_mfma_f32_16x16x32_bf16(av, bw[i], acc0, 0, 0, 0);
        }
        #pragma unroll
        for (int i = 12; i < 24; ++i) {
            const unsigned short* asrc = (i < 16)
                ? (h_sb + nn * 520 + i * 32 + q * 8)
                : (x_sb + nn * 264 + (i - 16) * 32 + q * 8);
            bf16x8 av = *(const bf16x8*)asrc;
            acc1 = __builtin_amdgcn_mfma_f32_16x16x32_bf16(av, bw[i], acc1, 0, 0, 0);
        }
        #pragma unroll
        for (int i = 0; i < 4; ++i) {
            const int kd = (w & 3) * 4 + i;
            bf16x8 av = *(const bf16x8*)(c_sb + nn * 520 + kd * 32 + q * 8);
            accd = __builtin_amdgcn_mfma_f32_16x16x32_bf16(av, bd[i], accd, 0, 0, 0);
        }

        // ---- gate epilogue in-register (no cross-wave reduce), d spill ----
        const int dt = w >> 2;
        #pragma unroll
        for (int r = 0; r < 4; ++r) {
            const int m = q * 4 + r;
            const float sv = acc0[r] + acc1[r] + bias_g;
            act[g * 512 + m * 32 + jj] = (g == 3) ? fast_tanh(sv) : fast_sigmoid(sv);
            Dred[dt][w & 3][m * 16 + ((nn + m) & 15)] = accd[r];
        }
        __syncthreads();

        // ---- d reduce (4-way) + decay ----
        {
            const int sl = rm * 16 + ((rn + rm) & 15);
            const float sv = Dred[rtl][0][sl] + Dred[rtl][1][sl]
                           + Dred[rtl][2][sl] + Dred[rtl][3][sl];
            cs1v[rm * 32 + rtl * 16 + rn] = fast_tanh(sv + bias_d);
        }
        if (t < 16)
            decv[t] = 1.0f / __logf(2.7182818284590452f + ts[(b0 + t) * Sdim + s]);
        __syncthreads();

        // ---- finale: all 512 threads, one (batch,col) unit each ----
        {
            const float dec  = decv[fm];
            const float cs1  = cs1v[t];
            const float cadj = (c_reg - cs1) + cs1 * dec;
            const float f  = act[t];
            const float ii = act[512 + t];
            const float oo = act[1024 + t];
            const float gg = act[1536 + t];
            const float cn = f * cadj + ii * gg;
            const float hn = oo * fast_tanh(cn);
            c_reg = cn;
            out[((size_t)(b0 + fm) * Sdim + s) * Hdim + j0 + fj] = hn;
            const float hn1 = __shfl_down(hn, 1);
            const float cn1 = __shfl_down(cn, 1);
            if (s < Sdim - 1) {
                if ((t & 1) == 0) {
                    unsigned* hmw = (unsigned*)(ws + WS_HMIR0 + ((s + 1) & 1) * 65536);
                    unsigned* cmw = (unsigned*)(ws + WS_CMIR0 + ((s + 1) & 1) * 65536);
                    const int didx = ((b0 + fm) * Hdim + j0 + fj) >> 1;
                    st_dev_u32(hmw + didx, pack2(hn, hn1));
                    st_dev_u32(cmw + didx, pack2(cn, cn1));
                }
            } else {
                float* hf = out + (size_t)Bdim * Sdim * Hdim;
                float* cf = hf + (size_t)Bdim * Hdim;
                hf[(b0 + fm) * Hdim + j0 + fj] = hn;
                cf[(b0 + fm) * Hdim + j0 + fj] = cn;
            }
        }

        if (s == Sdim - 1) break;

        __syncthreads();   // drains each wave's vmcnt -> mirror stores visible
        if (t == 0)
            __hip_atomic_store(&flags[blockIdx.x * FSTR], s + 1,
                               __ATOMIC_RELAXED, __HIP_MEMORY_SCOPE_AGENT);
        stage_x(s + 1);    // overlap with other WGs finishing
        if (t < 16) {      // 16-WG barrier within this bg group only
            while (__hip_atomic_load(&flags[(bg * 16 + t) * FSTR],
                                     __ATOMIC_RELAXED,
                                     __HIP_MEMORY_SCOPE_AGENT) < s + 1) {
                __builtin_amdgcn_s_sleep(1);
            }
        }
        __syncthreads();
    }
}

extern "C" void kernel_launch(void* const* d_in, const int* in_sizes, int n_in,
                              void* d_out, int out_size, void* d_ws, size_t ws_size,
                              hipStream_t stream) {
    const float* x      = (const float*)d_in[0];
    const float* ts     = (const float*)d_in[1];
    const float* Wall   = (const float*)d_in[2];
    const float* Wall_b = (const float*)d_in[3];
    const float* Uall   = (const float*)d_in[4];
    const float* Uall_b = (const float*)d_in[5];
    const float* Wd     = (const float*)d_in[6];
    const float* Wd_b   = (const float*)d_in[7];

    tlstm_prep<<<256, 256, 0, stream>>>(Wall, Uall, Wd, (unsigned char*)d_ws);
    tlstm_mfma<<<NWG, NT, 0, stream>>>(x, ts, Wall_b, Uall_b, Wd_b,
                                       (float*)d_out, (unsigned char*)d_ws);
}